// Round 10
// baseline (209.922 us; speedup 1.0000x reference)
//
#include <hip/hip_runtime.h>
#include <hip/hip_bf16.h>
#include <math.h>

// GAT x3 + LayerNorm for MI355X (gfx950).
// R21: deeper software pipeline in fused0/fused1 (R20's record prefetch gave
// -5us; extend one hop). (1) Rolling record prefetch: each chunk issues the
// next chunk's ebuf load; a node's last chunk issues the NEXT NODE's chunk-0
// record (also covers chunk-1 for deg>16 nodes, cold in R20). (2) Cross-node
// gather prefetch: during node s's reduce+epilogue, broadcast next node's
// srcs and issue its chunk-0 x/al gathers (fused0) or al gather + src
// broadcasts (fused1); chunk 0 peeled to consume prefetched operands.
// (3) Per-wave degree preload for next-node validity masks. Arithmetic,
// masks, and accumulation order bit-identical to R20.
// Carried: dedup Phase-A weights via shfl, early src broadcast, W0 in LDS,
// easum analytic self-loop, bucketed CSR (CAP=64) in k1, bf16 h,
// fused0=agg0+proj+gemm1, fused1=agg4+gemm2, al = A @ va extra MFMA col-tile.

typedef __attribute__((ext_vector_type(8))) short short8;
typedef __attribute__((ext_vector_type(4))) float float4v;

#define CAP 64

__device__ __forceinline__ float wave_sum(float v) {
#pragma unroll
  for (int off = 32; off > 0; off >>= 1) v += __shfl_xor(v, off, 64);
  return v;
}

__device__ __forceinline__ unsigned short f2bf(float v) {
  unsigned u = __float_as_uint(v);
  unsigned r = u + 0x7fff + ((u >> 16) & 1);  // RNE
  return (unsigned short)(r >> 16);
}

__device__ __forceinline__ float bf2f(unsigned short u) {
  return __uint_as_float(((unsigned)u) << 16);
}

__device__ __forceinline__ float sel4(float a, float b, float c, float d, int i) {
  return (i == 0) ? a : (i == 1) ? b : (i == 2) ? c : d;
}

// ---------------- K1 mega-dispatch ----------------
__global__ __launch_bounds__(256) void k1_kernel(
    const float* __restrict__ x, const int* __restrict__ srcv, const int* __restrict__ dstv,
    const float* __restrict__ eattr,
    const float* __restrict__ W0, const float* __restrict__ as0, const float* __restrict__ ad0,
    const float* __restrict__ We0, const float* __restrict__ ae0,
    const float* __restrict__ W1, const float* __restrict__ as1, const float* __restrict__ ad1,
    const float* __restrict__ We1, const float* __restrict__ ae1,
    const float* __restrict__ W2, const float* __restrict__ as2, const float* __restrict__ ad2,
    const float* __restrict__ We2, const float* __restrict__ ae2,
    unsigned short* __restrict__ Wf1, unsigned short* __restrict__ Wf2,
    float* __restrict__ wedot, float* __restrict__ al0s, float* __restrict__ al0d,
    int* __restrict__ deg, int2* __restrict__ ebuf,
    int N, int E, int gD) {
  int b = blockIdx.x;
  int tid = threadIdx.x;
  if (b < 272) {  // Wf1: 16 W1-tiles + 1 va1 tile, bf16 fragment order
    int idx = b * 256 + tid;
    int j = idx & 7, lane = (idx >> 3) & 63, ks = (idx >> 9) & 7, nt = idx >> 12;
    int k = ks * 32 + (lane >> 4) * 8 + j;
    int col = lane & 15;
    float v = 0.f;
    if (nt < 16) {
      v = W1[(size_t)k * 256 + nt * 16 + col];
    } else if (col < 4) {
      for (int c = 0; c < 64; c++) v = fmaf(W1[(size_t)k * 256 + col * 64 + c], as1[col * 64 + c], v);
    } else if (col < 8) {
      int h = col - 4;
      for (int c = 0; c < 64; c++) v = fmaf(W1[(size_t)k * 256 + h * 64 + c], ad1[h * 64 + c], v);
    }
    Wf1[idx] = f2bf(v);
  } else if (b < 352) {  // Wf2: 4 W2-tiles + 1 va2 tile
    int idx = (b - 272) * 256 + tid;
    int j = idx & 7, lane = (idx >> 3) & 63, ks = (idx >> 9) & 7, nt = idx >> 12;
    int k = ks * 32 + (lane >> 4) * 8 + j;
    int col = lane & 15;
    float v = 0.f;
    if (nt < 4) {
      v = W2[(size_t)k * 64 + nt * 16 + col];
    } else if (col < 1) {
      for (int c = 0; c < 64; c++) v = fmaf(W2[(size_t)k * 64 + c], as2[c], v);
    } else if (col < 2) {
      for (int c = 0; c < 64; c++) v = fmaf(W2[(size_t)k * 64 + c], ad2[c], v);
    }
    Wf2[idx] = f2bf(v);
  } else if (b == 352) {  // wedot
    if (tid >= 64) return;
    int c = tid;
    for (int h = 0; h < 4; h++) {
      float v = wave_sum(We0[h * 64 + c] * ae0[h * 64 + c]);
      if (c == 0) wedot[h] = v;
    }
    for (int h = 0; h < 4; h++) {
      float v = wave_sum(We1[h * 64 + c] * ae1[h * 64 + c]);
      if (c == 0) wedot[4 + h] = v;
    }
    float v = wave_sum(We2[c] * ae2[c]);
    if (c == 0) wedot[8] = v;
  } else if (b < 353 + gD) {  // layer-0 dots: al = x @ va0
    __shared__ float va[128];
    if (tid < 128) {
      int k = tid >> 3, col = tid & 7;
      float v = 0.f;
      if (col < 4) {
        for (int c = 0; c < 64; c++) v = fmaf(W0[(size_t)k * 256 + col * 64 + c], as0[col * 64 + c], v);
      } else {
        int h = col - 4;
        for (int c = 0; c < 64; c++) v = fmaf(W0[(size_t)k * 256 + h * 64 + c], ad0[h * 64 + c], v);
      }
      va[tid] = v;
    }
    __syncthreads();
    int node = (b - 353) * 256 + tid;
    if (node >= N) return;
    const float4* xr = (const float4*)(x + (size_t)node * 16);
    float4 xv[4];
#pragma unroll
    for (int q = 0; q < 4; q++) xv[q] = xr[q];
    float al[8];
#pragma unroll
    for (int j = 0; j < 8; j++) al[j] = 0.f;
#pragma unroll
    for (int k = 0; k < 16; k++) {
      float xk = ((const float*)xv)[k];
#pragma unroll
      for (int j = 0; j < 8; j++) al[j] = fmaf(xk, va[k * 8 + j], al[j]);
    }
    ((float4*)al0s)[node] = make_float4(al[0], al[1], al[2], al[3]);
    ((float4*)al0d)[node] = make_float4(al[4], al[5], al[6], al[7]);
  } else {  // degree count + bucket scatter (this IS the CSR fill)
    int e = (b - 353 - gD) * 256 + tid;
    if (e >= E) return;
    int d = dstv[e];
    int s = srcv[e];
    float ea = eattr[e];
    int pos = atomicAdd(&deg[d], 1);
    if (pos < CAP) ebuf[(size_t)d * CAP + pos] = make_int2(s, __float_as_int(ea));
  }
}

// fused0: layer-0 aggregate (rolling record prefetch + cross-node gather
// prefetch) + project -> LDS row, then block-level gemm1 -> buf256 + al1.
__global__ __launch_bounds__(256) void fused0_kernel(
    const int* __restrict__ deg, const int2* __restrict__ ebuf,
    const float* __restrict__ al0s, const float* __restrict__ al0d,
    const float* __restrict__ wedot,
    const float* __restrict__ x, const float* __restrict__ W0,
    const float* __restrict__ b0, const unsigned short* __restrict__ Wf1,
    unsigned short* __restrict__ buf256, float* __restrict__ al1s,
    float* __restrict__ al1d, int n) {
  __shared__ unsigned short hrow[16][264];  // 528B row stride
  __shared__ float w0lds[4096];             // W0 staged (16KB)
  int tile = blockIdx.x;
  int wv = threadIdx.x >> 6;
  int lane = threadIdx.x & 63;
  int es = lane >> 4;
  int c = lane & 15;
  int le = lane >> 2;   // Phase-A edge 0..15
  int lh = lane & 3;    // Phase-A head 0..3

  // stage W0 -> LDS (1024 float4s, 4 per thread)
#pragma unroll
  for (int i = 0; i < 4; i++) {
    int idx = i * 256 + threadIdx.x;
    ((float4*)w0lds)[idx] = ((const float4*)W0)[idx];
  }
  __syncthreads();

  float wd0 = wedot[0], wd1 = wedot[1], wd2 = wedot[2], wd3 = wedot[3];
  float wdP = sel4(wd0, wd1, wd2, wd3, lh);

  // preload degrees for this wave's 4 nodes
  int base0 = tile * 16 + wv * 4;
  int dgA[4];
#pragma unroll
  for (int t = 0; t < 4; t++) {
    int nd = base0 + t;
    dgA[t] = deg[nd < n ? nd : n - 1];
  }

  // ---- prologue: prefetch node 0 chunk 0 (record + src broadcast + gathers)
  int cnt0 = dgA[0] < CAP ? dgA[0] : CAP;
  int nodeC = base0 < n ? base0 : n - 1;
  int2 reC = ebuf[(size_t)nodeC * CAP + le];
  bool avP = le < cnt0;
  int srcEP = avP ? reC.x : 0;
  float evP = avP ? __int_as_float(reC.y) : 0.f;
  int srcKP[4];
  float xvKP[4];
#pragma unroll
  for (int k = 0; k < 4; k++) srcKP[k] = __shfl(srcEP, (k * 4 + es) * 4, 64);
#pragma unroll
  for (int k = 0; k < 4; k++) xvKP[k] = x[(size_t)srcKP[k] * 16 + c];
  float alvP = al0s[(size_t)srcEP * 4 + lh];

  for (int s = 0; s < 4; s++) {
    int r = wv * 4 + s;
    int node = tile * 16 + r;
    if (node < n) {
      int dg = dgA[s];
      int cnt = dg < CAP ? dg : CAP;
      int nextNode = node + 1 < n ? node + 1 : n - 1;
      int cntN = (s < 3) ? (dgA[s + 1] < CAP ? dgA[s + 1] : CAP) : 0;
      float xself = x[(size_t)node * 16 + c];
      float4 as4s = ((const float4*)al0s)[node];
      float4 ald4 = ((const float4*)al0d)[node];
      float aldP = sel4(ald4.x, ald4.y, ald4.z, ald4.w, lh);

      float Z[4] = {0.f, 0.f, 0.f, 0.f};
      float denP = 0.f;
      float easumP = 0.f;

      {  // ---- chunk 0 (prefetched operands); exact +0s when cnt==0
        size_t naddr = (16 < cnt) ? (size_t)node * CAP + 16 + le
                                  : (size_t)nextNode * CAP + le;
        int2 reN = ebuf[naddr];
        float a = alvP + aldP + evP * wdP;
        a = fmaxf(a, 0.2f * a);
        a = fminf(a, 30.f);
        float wE = avP ? __expf(a) : 0.f;
        denP += wE;
        easumP += (lh == 0) ? evP : 0.f;
#pragma unroll
        for (int k = 0; k < 4; k++) {
          int e4 = (k * 4 + es) * 4;
          float w0v = __shfl(wE, e4 + 0, 64);
          float w1v = __shfl(wE, e4 + 1, 64);
          float w2v = __shfl(wE, e4 + 2, 64);
          float w3v = __shfl(wE, e4 + 3, 64);
          Z[0] = fmaf(w0v, xvKP[k], Z[0]);
          Z[1] = fmaf(w1v, xvKP[k], Z[1]);
          Z[2] = fmaf(w2v, xvKP[k], Z[2]);
          Z[3] = fmaf(w3v, xvKP[k], Z[3]);
        }
        reC = reN;
      }

      for (int i = 16; i < cnt; i += 16) {  // ---- chunks 1+
        size_t naddr = (i + 16 < cnt) ? (size_t)node * CAP + i + 16 + le
                                      : (size_t)nextNode * CAP + le;
        int2 reN = ebuf[naddr];
        int slot = i + le;
        bool av = slot < cnt;
        int srcE = av ? reC.x : 0;
        float ev = av ? __int_as_float(reC.y) : 0.f;
        int srcK[4];
        float xvK[4];
#pragma unroll
        for (int k = 0; k < 4; k++) srcK[k] = __shfl(srcE, (k * 4 + es) * 4, 64);
#pragma unroll
        for (int k = 0; k < 4; k++) xvK[k] = x[(size_t)srcK[k] * 16 + c];
        float a = al0s[(size_t)srcE * 4 + lh] + aldP + ev * wdP;
        a = fmaxf(a, 0.2f * a);
        a = fminf(a, 30.f);
        float wE = av ? __expf(a) : 0.f;
        denP += wE;
        easumP += (lh == 0) ? ev : 0.f;
#pragma unroll
        for (int k = 0; k < 4; k++) {
          int e4 = (k * 4 + es) * 4;
          float w0v = __shfl(wE, e4 + 0, 64);
          float w1v = __shfl(wE, e4 + 1, 64);
          float w2v = __shfl(wE, e4 + 2, 64);
          float w3v = __shfl(wE, e4 + 3, 64);
          Z[0] = fmaf(w0v, xvK[k], Z[0]);
          Z[1] = fmaf(w1v, xvK[k], Z[1]);
          Z[2] = fmaf(w2v, xvK[k], Z[2]);
          Z[3] = fmaf(w3v, xvK[k], Z[3]);
        }
        reC = reN;
      }

      {  // ---- cross-node prefetch (overlaps reduce + epilogue below)
        bool av2 = le < cntN;
        int srcE2 = av2 ? reC.x : 0;
        avP = av2;
        evP = av2 ? __int_as_float(reC.y) : 0.f;
#pragma unroll
        for (int k = 0; k < 4; k++) srcKP[k] = __shfl(srcE2, (k * 4 + es) * 4, 64);
#pragma unroll
        for (int k = 0; k < 4; k++) xvKP[k] = x[(size_t)srcKP[k] * 16 + c];
        alvP = al0s[(size_t)srcE2 * 4 + lh];
      }

      // reduce Z over the 4 es-groups (same order as R20)
#pragma unroll
      for (int h = 0; h < 4; h++) {
        Z[h] += __shfl_xor(Z[h], 16, 64);
        Z[h] += __shfl_xor(Z[h], 32, 64);
      }
      denP += __shfl_xor(denP, 4, 64);
      denP += __shfl_xor(denP, 8, 64);
      denP += __shfl_xor(denP, 16, 64);
      denP += __shfl_xor(denP, 32, 64);
      float easum = wave_sum(easumP);

      // per-lane head = es: den total + self loop (single exp)
      float dsel = __shfl(denP, es, 64);
      float evs = easum / fmaxf((float)dg, 1.f);
      float as_e = sel4(as4s.x, as4s.y, as4s.z, as4s.w, es);
      float ald_e = sel4(ald4.x, ald4.y, ald4.z, ald4.w, es);
      float wd_e = sel4(wd0, wd1, wd2, wd3, es);
      float aS = as_e + ald_e + evs * wd_e;
      aS = fmaxf(aS, 0.2f * aS);
      aS = fminf(aS, 30.f);
      float wvs = __expf(aS);
      dsel += wvs;
      float zsel = sel4(Z[0], Z[1], Z[2], Z[3], es) + wvs * xself;
      float zn = zsel / (dsel + 1e-16f);

      float zc[16];
      int basel = lane & 48;
#pragma unroll
      for (int cc = 0; cc < 16; cc++) zc[cc] = __shfl(zn, basel + cc, 64);
      float o[4];
      float4 b4 = ((const float4*)b0)[lane];
#pragma unroll
      for (int jj = 0; jj < 4; jj++) o[jj] = ((const float*)&b4)[jj];
#pragma unroll
      for (int cc = 0; cc < 16; cc++) {
        float4 w0r = *(const float4*)&w0lds[cc * 256 + lane * 4];
#pragma unroll
        for (int jj = 0; jj < 4; jj++) o[jj] = fmaf(zc[cc], ((const float*)&w0r)[jj], o[jj]);
      }
      ushort4 o4;
      float ox = o[0] > 0.f ? o[0] : expm1f(o[0]);
      float oy = o[1] > 0.f ? o[1] : expm1f(o[1]);
      float oz = o[2] > 0.f ? o[2] : expm1f(o[2]);
      float ow = o[3] > 0.f ? o[3] : expm1f(o[3]);
      o4.x = f2bf(ox);
      o4.y = f2bf(oy);
      o4.z = f2bf(oz);
      o4.w = f2bf(ow);
      *(ushort4*)&hrow[r][lane * 4] = o4;
    } else {
      *(ushort4*)&hrow[r][lane * 4] = make_ushort4(0, 0, 0, 0);
    }
  }
  __syncthreads();

  // ---- block-level gemm1 over the 16-row LDS tile
  int m = lane & 15, q = lane >> 4;
  int row0 = tile * 16;
  short8 afrag[8];
#pragma unroll
  for (int ks = 0; ks < 8; ks++) afrag[ks] = *(short8*)&hrow[m][ks * 32 + q * 8];

  const short8* wf = (const short8*)Wf1;
  for (int nt = wv; nt < 17; nt += 4) {
    const short8* bl = wf + (size_t)nt * 8 * 64 + lane;
    short8 bf[8];
#pragma unroll
    for (int ks = 0; ks < 8; ks++) bf[ks] = bl[ks * 64];
    float4v acc = {0.f, 0.f, 0.f, 0.f};
#pragma unroll
    for (int ks = 0; ks < 8; ks++)
      acc = __builtin_amdgcn_mfma_f32_16x16x32_bf16(afrag[ks], bf[ks], acc, 0, 0, 0);
    if (nt < 16) {
      int col = nt * 16 + m;
#pragma unroll
      for (int reg = 0; reg < 4; reg++) {
        int rr = row0 + q * 4 + reg;
        if (rr < n) buf256[(size_t)rr * 256 + col] = f2bf(acc[reg]);
      }
    } else {
#pragma unroll
      for (int reg = 0; reg < 4; reg++) {
        int rr = row0 + q * 4 + reg;
        if (rr < n) {
          if (m < 4) al1s[(size_t)rr * 4 + m] = acc[reg];
          else if (m < 8) al1d[(size_t)rr * 4 + (m - 4)] = acc[reg];
        }
      }
    }
  }
}

// fused1: layer-1 aggregation (rolling record prefetch + cross-node src/al
// prefetch) -> LDS row, then gemm2 -> buf64 + al2s/al2d.
__global__ __launch_bounds__(256) void fused1_kernel(
    const int* __restrict__ deg, const int2* __restrict__ ebuf,
    const float* __restrict__ al1s, const float* __restrict__ al1d,
    const float* __restrict__ wedot,
    const unsigned short* __restrict__ buf256, const float* __restrict__ b1,
    const unsigned short* __restrict__ Wf2, unsigned short* __restrict__ buf64,
    float* __restrict__ al2s, float* __restrict__ al2d, int n) {
  __shared__ unsigned short hrow[16][264];  // 528B row stride
  int tile = blockIdx.x;
  int wv = threadIdx.x >> 6;
  int lane = threadIdx.x & 63;
  int half = lane >> 5;
  int l = lane & 31;
  int h4 = l >> 3;
  int le = lane >> 2;
  int lh = lane & 3;
  int eA0 = half ? 1 : 0;  // Phase-B edge offsets
  int eB0 = half ? 3 : 2;

  float wdh = wedot[4 + h4];
  float wdP = wedot[4 + lh];

  int base0 = tile * 16 + wv * 4;
  int dgA[4];
#pragma unroll
  for (int t = 0; t < 4; t++) {
    int nd = base0 + t;
    dgA[t] = deg[nd < n ? nd : n - 1];
  }

  // ---- prologue: prefetch node 0 chunk 0 (record + src broadcasts + al)
  int cnt0 = dgA[0] < CAP ? dgA[0] : CAP;
  int nodeC = base0 < n ? base0 : n - 1;
  int2 reC = ebuf[(size_t)nodeC * CAP + le];
  bool avP = le < cnt0;
  int srcEP = avP ? reC.x : 0;
  float evP = avP ? __int_as_float(reC.y) : 0.f;
  int srcAP[4], srcBP[4];
#pragma unroll
  for (int k = 0; k < 4; k++) {
    srcAP[k] = __shfl(srcEP, (k * 4 + eA0) * 4, 64);
    srcBP[k] = __shfl(srcEP, (k * 4 + eB0) * 4, 64);
  }
  float alvP = al1s[(size_t)srcEP * 4 + lh];

  for (int s = 0; s < 4; s++) {
    int r = wv * 4 + s;
    int node = tile * 16 + r;
    if (node < n) {
      int dg = dgA[s];
      int cnt = dg < CAP ? dg : CAP;
      int nextNode = node + 1 < n ? node + 1 : n - 1;
      int cntN = (s < 3) ? (dgA[s + 1] < CAP ? dgA[s + 1] : CAP) : 0;
      float aldh = al1d[(size_t)node * 4 + h4];
      float alsh = al1s[(size_t)node * 4 + h4];
      float aldP = al1d[(size_t)node * 4 + lh];
      short8 rowS = ((const short8*)(buf256 + (size_t)node * 256))[l];

      float acc[8];
#pragma unroll
      for (int j = 0; j < 8; j++) acc[j] = 0.f;
      float denP = 0.f;
      float easumP = 0.f;

      {  // ---- chunk 0 (prefetched record/srcs/al); exact +0s when cnt==0
        size_t naddr = (16 < cnt) ? (size_t)node * CAP + 16 + le
                                  : (size_t)nextNode * CAP + le;
        int2 reN = ebuf[naddr];
        short8 rowA[4], rowB[4];
#pragma unroll
        for (int k = 0; k < 4; k++) {
          rowA[k] = ((const short8*)(buf256 + (size_t)srcAP[k] * 256))[l];
          rowB[k] = ((const short8*)(buf256 + (size_t)srcBP[k] * 256))[l];
        }
        float a = alvP + aldP + evP * wdP;
        a = fmaxf(a, 0.2f * a);
        a = fminf(a, 30.f);
        float wE = avP ? __expf(a) : 0.f;
        denP += wE;
        easumP += (lh == 0) ? evP : 0.f;
#pragma unroll
        for (int k = 0; k < 4; k++) {
          float wA = __shfl(wE, (k * 4 + eA0) * 4 + h4, 64);
          float wB = __shfl(wE, (k * 4 + eB0) * 4 + h4, 64);
          const unsigned short* pa = (const unsigned short*)&rowA[k];
          const unsigned short* pb = (const unsigned short*)&rowB[k];
#pragma unroll
          for (int j = 0; j < 8; j++) acc[j] = fmaf(wA, bf2f(pa[j]), acc[j]);
#pragma unroll
          for (int j = 0; j < 8; j++) acc[j] = fmaf(wB, bf2f(pb[j]), acc[j]);
        }
        reC = reN;
      }

      for (int i = 16; i < cnt; i += 16) {  // ---- chunks 1+
        size_t naddr = (i + 16 < cnt) ? (size_t)node * CAP + i + 16 + le
                                      : (size_t)nextNode * CAP + le;
        int2 reN = ebuf[naddr];
        int slot = i + le;
        bool av = slot < cnt;
        int srcE = av ? reC.x : 0;
        float ev = av ? __int_as_float(reC.y) : 0.f;
        int srcA[4], srcB[4];
#pragma unroll
        for (int k = 0; k < 4; k++) {
          srcA[k] = __shfl(srcE, (k * 4 + eA0) * 4, 64);
          srcB[k] = __shfl(srcE, (k * 4 + eB0) * 4, 64);
        }
        short8 rowA[4], rowB[4];
#pragma unroll
        for (int k = 0; k < 4; k++) {
          rowA[k] = ((const short8*)(buf256 + (size_t)srcA[k] * 256))[l];
          rowB[k] = ((const short8*)(buf256 + (size_t)srcB[k] * 256))[l];
        }
        float a = al1s[(size_t)srcE * 4 + lh] + aldP + ev * wdP;
        a = fmaxf(a, 0.2f * a);
        a = fminf(a, 30.f);
        float wE = av ? __expf(a) : 0.f;
        denP += wE;
        easumP += (lh == 0) ? ev : 0.f;
#pragma unroll
        for (int k = 0; k < 4; k++) {
          float wA = __shfl(wE, (k * 4 + eA0) * 4 + h4, 64);
          float wB = __shfl(wE, (k * 4 + eB0) * 4 + h4, 64);
          const unsigned short* pa = (const unsigned short*)&rowA[k];
          const unsigned short* pb = (const unsigned short*)&rowB[k];
#pragma unroll
          for (int j = 0; j < 8; j++) acc[j] = fmaf(wA, bf2f(pa[j]), acc[j]);
#pragma unroll
          for (int j = 0; j < 8; j++) acc[j] = fmaf(wB, bf2f(pb[j]), acc[j]);
        }
        reC = reN;
      }

      {  // ---- cross-node prefetch (overlaps reduce + epilogue below)
        bool av2 = le < cntN;
        int srcE2 = av2 ? reC.x : 0;
        avP = av2;
        evP = av2 ? __int_as_float(reC.y) : 0.f;
#pragma unroll
        for (int k = 0; k < 4; k++) {
          srcAP[k] = __shfl(srcE2, (k * 4 + eA0) * 4, 64);
          srcBP[k] = __shfl(srcE2, (k * 4 + eB0) * 4, 64);
        }
        alvP = al1s[(size_t)srcE2 * 4 + lh];
      }

      // merge halves (same as R20)
#pragma unroll
      for (int j = 0; j < 8; j++) acc[j] += __shfl_xor(acc[j], 32, 64);
      denP += __shfl_xor(denP, 4, 64);
      denP += __shfl_xor(denP, 8, 64);
      denP += __shfl_xor(denP, 16, 64);
      denP += __shfl_xor(denP, 32, 64);
      float easum = wave_sum(easumP);
      float den = __shfl(denP, h4, 64);

      {  // self loop (single exp per lane, head h4)
        float evs = easum / fmaxf((float)dg, 1.f);
        float a = alsh + aldh + evs * wdh;
        a = fmaxf(a, 0.2f * a);
        a = fminf(a, 30.f);
        float wvv = __expf(a);
        const unsigned short* ps = (const unsigned short*)&rowS;
        den += wvv;
#pragma unroll
        for (int j = 0; j < 8; j++) acc[j] = fmaf(wvv, bf2f(ps[j]), acc[j]);
      }

      if (half == 0) {
        float inv = 1.f / (den + 1e-16f);
        float4 bb0 = ((const float4*)b1)[l * 2];
        float4 bb1 = ((const float4*)b1)[l * 2 + 1];
        unsigned short o8[8];
#pragma unroll
        for (int j = 0; j < 8; j++) {
          float bjv = (j < 4) ? ((const float*)&bb0)[j] : ((const float*)&bb1)[j - 4];
          float o = acc[j] * inv + bjv;
          o = o > 0.f ? o : expm1f(o);
          o8[j] = f2bf(o);
        }
        *(short8*)&hrow[r][l * 8] = *(short8*)o8;
      }
    } else if (half == 0) {
      unsigned short z8[8] = {0, 0, 0, 0, 0, 0, 0, 0};
      *(short8*)&hrow[r][l * 8] = *(short8*)z8;
    }
  }
  __syncthreads();

  // ---- block-level gemm2 over the 16-row LDS tile
  int m = lane & 15, q = lane >> 4;
  int row0 = tile * 16;
  short8 afrag[8];
#pragma unroll
  for (int ks = 0; ks < 8; ks++) afrag[ks] = *(short8*)&hrow[m][ks * 32 + q * 8];

  const short8* wf = (const short8*)Wf2;
  for (int nt = wv; nt < 5; nt += 4) {
    const short8* bl = wf + (size_t)nt * 8 * 64 + lane;
    short8 bf[8];
#pragma unroll
    for (int ks = 0; ks < 8; ks++) bf[ks] = bl[ks * 64];
    float4v acc = {0.f, 0.f, 0.f, 0.f};
#pragma unroll
    for (int ks = 0; ks < 8; ks++)
      acc = __builtin_amdgcn_mfma_f32_16x16x32_bf16(afrag[ks], bf[ks], acc, 0, 0, 0);
    if (nt < 4) {
      int col = nt * 16 + m;
#pragma unroll
      for (int reg = 0; reg < 4; reg++) {
        int rr = row0 + q * 4 + reg;
        if (rr < n) buf64[(size_t)rr * 64 + col] = f2bf(acc[reg]);
      }
    } else {
#pragma unroll
      for (int reg = 0; reg < 4; reg++) {
        int rr = row0 + q * 4 + reg;
        if (rr < n) {
          if (m < 1) al2s[rr] = acc[reg];
          else if (m < 2) al2d[rr] = acc[reg];
        }
      }
    }
  }
}

// H=1 aggregation (shfl weights, early gathers) + bias + LayerNorm.
__global__ __launch_bounds__(256) void agg_ln_kernel(
    const int* __restrict__ deg, const int2* __restrict__ ebuf,
    const float* __restrict__ al2s, const float* __restrict__ al2d,
    const float* __restrict__ wedot,
    const unsigned short* __restrict__ B, const float* __restrict__ bias,
    const float* __restrict__ ln_g, const float* __restrict__ ln_b,
    float* __restrict__ out, int n) {
  int wv = threadIdx.x >> 6;
  int node = blockIdx.x * 4 + wv;
  if (node >= n) return;
  int lane = threadIdx.x & 63;
  int q = lane >> 4;
  int l = lane & 15;
  int le = lane & 15;  // Phase-A edge (4x redundant groups; exact dup-sum)
  int dg = deg[node];
  int cnt = dg < CAP ? dg : CAP;
  float ald = al2d[node];
  float als = al2s[node];
  float wd = wedot[0];
  ushort4 bvS = ((const ushort4*)(B + (size_t)node * 64))[l];

  float4 acc = make_float4(0.f, 0.f, 0.f, 0.f);
  float denP = 0.f;
  float easumP = 0.f;

  for (int i = 0; i < cnt; i += 16) {
    int slot = i + le;
    bool av = slot < cnt;
    int2 re = ebuf[(size_t)node * CAP + slot];
    int srcE = av ? re.x : 0;
    float ev = av ? __int_as_float(re.y) : 0.f;
    int srcK[4];
#pragma unroll
    for (int k = 0; k < 4; k++) srcK[k] = __shfl(srcE, k * 4 + q, 64);
    ushort4 bvK[4];
#pragma unroll
    for (int k = 0; k < 4; k++) bvK[k] = ((const ushort4*)(B + (size_t)srcK[k] * 64))[l];
    float a = al2s[srcE] + ald + ev * wd;
    a = fmaxf(a, 0.2f * a);
    a = fminf(a, 30.f);
    float wE = av ? __expf(a) : 0.f;
    denP += wE;    // 4 copies per edge -> exact /4 later
    easumP += ev;  // ditto
#pragma unroll
    for (int k = 0; k < 4; k++) {
      float w = __shfl(wE, k * 4 + q, 64);
      acc.x = fmaf(w, bf2f(bvK[k].x), acc.x);
      acc.y = fmaf(w, bf2f(bvK[k].y), acc.y);
      acc.z = fmaf(w, bf2f(bvK[k].z), acc.z);
      acc.w = fmaf(w, bf2f(bvK[k].w), acc.w);
    }
  }

  acc.x += __shfl_xor(acc.x, 32, 64);
  acc.y += __shfl_xor(acc.y, 32, 64);
  acc.z += __shfl_xor(acc.z, 32, 64);
  acc.w += __shfl_xor(acc.w, 32, 64);
  acc.x += __shfl_xor(acc.x, 16, 64);
  acc.y += __shfl_xor(acc.y, 16, 64);
  acc.z += __shfl_xor(acc.z, 16, 64);
  acc.w += __shfl_xor(acc.w, 16, 64);
  float den = wave_sum(denP) * 0.25f;
  float easum = wave_sum(easumP) * 0.25f;

  {  // self loop (single exp)
    float evs = easum / fmaxf((float)dg, 1.f);
    float a = als + ald + evs * wd;
    a = fmaxf(a, 0.2f * a);
    a = fminf(a, 30.f);
    float wv2 = __expf(a);
    den += wv2;
    acc.x = fmaf(wv2, bf2f(bvS.x), acc.x);
    acc.y = fmaf(wv2, bf2f(bvS.y), acc.y);
    acc.z = fmaf(wv2, bf2f(bvS.z), acc.z);
    acc.w = fmaf(wv2, bf2f(bvS.w), acc.w);
  }

  float inv = 1.f / (den + 1e-16f);
  float4 b4 = ((const float4*)bias)[l];
  float4 o;
  o.x = acc.x * inv + b4.x;
  o.y = acc.y * inv + b4.y;
  o.z = acc.z * inv + b4.z;
  o.w = acc.w * inv + b4.w;
  float s = (o.x + o.y) + (o.z + o.w);
#pragma unroll
  for (int off = 1; off < 16; off <<= 1) s += __shfl_xor(s, off, 64);
  float mu = s * (1.f / 64.f);
  float dx = o.x - mu, dy = o.y - mu, dz = o.z - mu, dw = o.w - mu;
  float v = (dx * dx + dy * dy) + (dz * dz + dw * dw);
#pragma unroll
  for (int off = 1; off < 16; off <<= 1) v += __shfl_xor(v, off, 64);
  float rs = rsqrtf(v * (1.f / 64.f) + 1e-5f);
  if (q == 0) {
    float4 g4 = ((const float4*)ln_g)[l];
    float4 lb4 = ((const float4*)ln_b)[l];
    float4 rr;
    rr.x = dx * rs * g4.x + lb4.x;
    rr.y = dy * rs * g4.y + lb4.y;
    rr.z = dz * rs * g4.z + lb4.z;
    rr.w = dw * rs * g4.w + lb4.w;
    ((float4*)(out + (size_t)node * 64))[l] = rr;
  }
}

extern "C" void kernel_launch(void* const* d_in, const int* in_sizes, int n_in,
                              void* d_out, int out_size, void* d_ws, size_t ws_size,
                              hipStream_t stream) {
  const float* x = (const float*)d_in[0];
  const int* ei = (const int*)d_in[1];
  const float* eattr = (const float*)d_in[2];
  const float* W0 = (const float*)d_in[3];
  const float* as0 = (const float*)d_in[4];
  const float* ad0 = (const float*)d_in[5];
  const float* We0 = (const float*)d_in[6];
  const float* ae0 = (const float*)d_in[7];
  const float* b0 = (const float*)d_in[8];
  const float* W1 = (const float*)d_in[9];
  const float* as1 = (const float*)d_in[10];
  const float* ad1 = (const float*)d_in[11];
  const float* We1 = (const float*)d_in[12];
  const float* ae1 = (const float*)d_in[13];
  const float* b1 = (const float*)d_in[14];
  const float* W2 = (const float*)d_in[15];
  const float* as2 = (const float*)d_in[16];
  const float* ad2 = (const float*)d_in[17];
  const float* We2 = (const float*)d_in[18];
  const float* ae2 = (const float*)d_in[19];
  const float* b2 = (const float*)d_in[20];
  const float* lng = (const float*)d_in[21];
  const float* lnb = (const float*)d_in[22];
  float* outp = (float*)d_out;

  const int N = in_sizes[0] / 16;
  const int E = in_sizes[1] / 2;
  const int* srcv = ei;
  const int* dstv = ei + E;

  char* w = (char*)d_ws;
  size_t off = 0;
  auto alloc = [&](size_t bytes) -> void* {
    void* p = w + off;
    off += (bytes + 255) & ~(size_t)255;
    return p;
  };
  int* deg = (int*)alloc((size_t)N * 4);
  size_t zero_bytes = off;  // deg must start at 0
  int2* ebuf = (int2*)alloc(((size_t)N * CAP + 16) * 8);  // +16: overread pad
  float* wedot = (float*)alloc(16 * 4);
  float* al0s = (float*)alloc((size_t)N * 4 * 4);
  float* al0d = (float*)alloc((size_t)N * 4 * 4);
  float* al1s = (float*)alloc((size_t)N * 4 * 4);
  float* al1d = (float*)alloc((size_t)N * 4 * 4);
  float* al2s = (float*)alloc((size_t)N * 4);
  float* al2d = (float*)alloc((size_t)N * 4);
  unsigned short* Wf1 = (unsigned short*)alloc((size_t)17 * 4096 * 2);
  unsigned short* Wf2 = (unsigned short*)alloc((size_t)5 * 4096 * 2);
  unsigned short* buf256 = (unsigned short*)alloc((size_t)N * 256 * 2);
  unsigned short* buf64 = (unsigned short*)alloc((size_t)N * 64 * 2);
  (void)ws_size;

  hipMemsetAsync(d_ws, 0, zero_bytes, stream);

  int gE = (E + 255) / 256;
  int gD = (N + 255) / 256;

  k1_kernel<<<353 + gD + gE, 256, 0, stream>>>(
      x, srcv, dstv, eattr, W0, as0, ad0, We0, ae0, W1, as1, ad1, We1, ae1,
      W2, as2, ad2, We2, ae2, Wf1, Wf2, wedot, al0s, al0d, deg, ebuf, N, E, gD);

  int gT = (N + 15) / 16;
  int gNode4 = (N + 3) / 4;

  // ---- layer 0 + gemm1 fused
  fused0_kernel<<<gT, 256, 0, stream>>>(deg, ebuf, al0s, al0d, wedot, x, W0, b0,
                                        Wf1, buf256, al1s, al1d, N);

  // ---- layer 1 + gemm2 fused
  fused1_kernel<<<gT, 256, 0, stream>>>(deg, ebuf, al1s, al1d, wedot, buf256, b1,
                                        Wf2, buf64, al2s, al2d, N);

  // ---- layer 2 (+ LayerNorm -> d_out)
  agg_ln_kernel<<<gNode4, 256, 0, stream>>>(deg, ebuf, al2s, al2d, wedot + 8,
                                            buf64, b2, lng, lnb, outp, N);
}

// Round 11
// 201.808 us; speedup vs baseline: 1.0402x; 1.0402x over previous
//
#include <hip/hip_runtime.h>
#include <hip/hip_bf16.h>
#include <math.h>

// GAT x3 + LayerNorm for MI355X (gfx950).
// R22: REVERT R21 (deeper pipeline cost VGPR 72->88, occupancy 21->15%,
// net -4.6us). Base = R20 (best, 205.3us). Delta: ebuf re-laid out
// CHUNK-MAJOR -- record for slot p of node d at ((p>>4)*N + d)*16 + (p&15).
// Chunk-0 records of all nodes become a dense 2.56MB region: node+1's
// chunk-0 (the R20 cross-node prefetch target) is the ADJACENT 128B, a
// wave's 4 nodes read 512B contiguous, and the hot region stays L2-resident
// across all three agg kernels. Addressing-only change; slot occupancy,
// masks, arithmetic bit-identical to R20.
// Carried: cross-node record prefetch (R20), dedup Phase-A weights via shfl,
// early src broadcast, W0 staged in LDS, easum analytic self-loop, bucketed
// CSR (CAP=64) in k1, bf16 h, fused0=agg0+proj+gemm1, fused1=agg4+gemm2,
// al = A @ va extra MFMA col-tile.

typedef __attribute__((ext_vector_type(8))) short short8;
typedef __attribute__((ext_vector_type(4))) float float4v;

#define CAP 64

__device__ __forceinline__ float wave_sum(float v) {
#pragma unroll
  for (int off = 32; off > 0; off >>= 1) v += __shfl_xor(v, off, 64);
  return v;
}

__device__ __forceinline__ unsigned short f2bf(float v) {
  unsigned u = __float_as_uint(v);
  unsigned r = u + 0x7fff + ((u >> 16) & 1);  // RNE
  return (unsigned short)(r >> 16);
}

__device__ __forceinline__ float bf2f(unsigned short u) {
  return __uint_as_float(((unsigned)u) << 16);
}

__device__ __forceinline__ float sel4(float a, float b, float c, float d, int i) {
  return (i == 0) ? a : (i == 1) ? b : (i == 2) ? c : d;
}

// chunk-major ebuf index: slot p of node d -> ((p>>4)*N + d)*16 + (p&15)
__device__ __forceinline__ size_t eidx(int node, int chunk, int rec, int N) {
  return ((size_t)chunk * N + node) * 16 + rec;
}

// ---------------- K1 mega-dispatch ----------------
__global__ __launch_bounds__(256) void k1_kernel(
    const float* __restrict__ x, const int* __restrict__ srcv, const int* __restrict__ dstv,
    const float* __restrict__ eattr,
    const float* __restrict__ W0, const float* __restrict__ as0, const float* __restrict__ ad0,
    const float* __restrict__ We0, const float* __restrict__ ae0,
    const float* __restrict__ W1, const float* __restrict__ as1, const float* __restrict__ ad1,
    const float* __restrict__ We1, const float* __restrict__ ae1,
    const float* __restrict__ W2, const float* __restrict__ as2, const float* __restrict__ ad2,
    const float* __restrict__ We2, const float* __restrict__ ae2,
    unsigned short* __restrict__ Wf1, unsigned short* __restrict__ Wf2,
    float* __restrict__ wedot, float* __restrict__ al0s, float* __restrict__ al0d,
    int* __restrict__ deg, int2* __restrict__ ebuf,
    int N, int E, int gD) {
  int b = blockIdx.x;
  int tid = threadIdx.x;
  if (b < 272) {  // Wf1: 16 W1-tiles + 1 va1 tile, bf16 fragment order
    int idx = b * 256 + tid;
    int j = idx & 7, lane = (idx >> 3) & 63, ks = (idx >> 9) & 7, nt = idx >> 12;
    int k = ks * 32 + (lane >> 4) * 8 + j;
    int col = lane & 15;
    float v = 0.f;
    if (nt < 16) {
      v = W1[(size_t)k * 256 + nt * 16 + col];
    } else if (col < 4) {
      for (int c = 0; c < 64; c++) v = fmaf(W1[(size_t)k * 256 + col * 64 + c], as1[col * 64 + c], v);
    } else if (col < 8) {
      int h = col - 4;
      for (int c = 0; c < 64; c++) v = fmaf(W1[(size_t)k * 256 + h * 64 + c], ad1[h * 64 + c], v);
    }
    Wf1[idx] = f2bf(v);
  } else if (b < 352) {  // Wf2: 4 W2-tiles + 1 va2 tile
    int idx = (b - 272) * 256 + tid;
    int j = idx & 7, lane = (idx >> 3) & 63, ks = (idx >> 9) & 7, nt = idx >> 12;
    int k = ks * 32 + (lane >> 4) * 8 + j;
    int col = lane & 15;
    float v = 0.f;
    if (nt < 4) {
      v = W2[(size_t)k * 64 + nt * 16 + col];
    } else if (col < 1) {
      for (int c = 0; c < 64; c++) v = fmaf(W2[(size_t)k * 64 + c], as2[c], v);
    } else if (col < 2) {
      for (int c = 0; c < 64; c++) v = fmaf(W2[(size_t)k * 64 + c], ad2[c], v);
    }
    Wf2[idx] = f2bf(v);
  } else if (b == 352) {  // wedot
    if (tid >= 64) return;
    int c = tid;
    for (int h = 0; h < 4; h++) {
      float v = wave_sum(We0[h * 64 + c] * ae0[h * 64 + c]);
      if (c == 0) wedot[h] = v;
    }
    for (int h = 0; h < 4; h++) {
      float v = wave_sum(We1[h * 64 + c] * ae1[h * 64 + c]);
      if (c == 0) wedot[4 + h] = v;
    }
    float v = wave_sum(We2[c] * ae2[c]);
    if (c == 0) wedot[8] = v;
  } else if (b < 353 + gD) {  // layer-0 dots: al = x @ va0
    __shared__ float va[128];
    if (tid < 128) {
      int k = tid >> 3, col = tid & 7;
      float v = 0.f;
      if (col < 4) {
        for (int c = 0; c < 64; c++) v = fmaf(W0[(size_t)k * 256 + col * 64 + c], as0[col * 64 + c], v);
      } else {
        int h = col - 4;
        for (int c = 0; c < 64; c++) v = fmaf(W0[(size_t)k * 256 + h * 64 + c], ad0[h * 64 + c], v);
      }
      va[tid] = v;
    }
    __syncthreads();
    int node = (b - 353) * 256 + tid;
    if (node >= N) return;
    const float4* xr = (const float4*)(x + (size_t)node * 16);
    float4 xv[4];
#pragma unroll
    for (int q = 0; q < 4; q++) xv[q] = xr[q];
    float al[8];
#pragma unroll
    for (int j = 0; j < 8; j++) al[j] = 0.f;
#pragma unroll
    for (int k = 0; k < 16; k++) {
      float xk = ((const float*)xv)[k];
#pragma unroll
      for (int j = 0; j < 8; j++) al[j] = fmaf(xk, va[k * 8 + j], al[j]);
    }
    ((float4*)al0s)[node] = make_float4(al[0], al[1], al[2], al[3]);
    ((float4*)al0d)[node] = make_float4(al[4], al[5], al[6], al[7]);
  } else {  // degree count + chunk-major bucket scatter (this IS the CSR fill)
    int e = (b - 353 - gD) * 256 + tid;
    if (e >= E) return;
    int d = dstv[e];
    int s = srcv[e];
    float ea = eattr[e];
    int pos = atomicAdd(&deg[d], 1);
    if (pos < CAP) ebuf[eidx(d, pos >> 4, pos & 15, N)] = make_int2(s, __float_as_int(ea));
  }
}

// fused0: layer-0 aggregate (shfl weights, early x-gathers, cross-node
// prefetch) + project -> LDS row, then block-level 16-row MFMA gemm1 ->
// buf256 + al1s/al1d.
__global__ __launch_bounds__(256) void fused0_kernel(
    const int* __restrict__ deg, const int2* __restrict__ ebuf,
    const float* __restrict__ al0s, const float* __restrict__ al0d,
    const float* __restrict__ wedot,
    const float* __restrict__ x, const float* __restrict__ W0,
    const float* __restrict__ b0, const unsigned short* __restrict__ Wf1,
    unsigned short* __restrict__ buf256, float* __restrict__ al1s,
    float* __restrict__ al1d, int n) {
  __shared__ unsigned short hrow[16][264];  // 528B row stride
  __shared__ float w0lds[4096];             // W0 staged (16KB)
  int tile = blockIdx.x;
  int wv = threadIdx.x >> 6;
  int lane = threadIdx.x & 63;
  int es = lane >> 4;
  int c = lane & 15;
  int le = lane >> 2;   // Phase-A edge 0..15
  int lh = lane & 3;    // Phase-A head 0..3

  // stage W0 -> LDS (1024 float4s, 4 per thread)
#pragma unroll
  for (int i = 0; i < 4; i++) {
    int idx = i * 256 + threadIdx.x;
    ((float4*)w0lds)[idx] = ((const float4*)W0)[idx];
  }
  __syncthreads();

  // cross-node prefetch: node s+1's first record issued before node s's
  // reduce+epilogue (hides top-of-chain latency). Chunk-major: adjacent 128B.
  int node0 = tile * 16 + wv * 4;
  int2 preRe = ebuf[eidx(node0 < n ? node0 : n - 1, 0, le, n)];

  for (int s = 0; s < 4; s++) {
    int r = wv * 4 + s;
    int node = tile * 16 + r;
    if (node < n) {
      int dg = deg[node];
      int cnt = dg < CAP ? dg : CAP;
      float xself = x[(size_t)node * 16 + c];
      float4 as4s = ((const float4*)al0s)[node];
      float4 ald4 = ((const float4*)al0d)[node];
      float aldP = sel4(ald4.x, ald4.y, ald4.z, ald4.w, lh);
      float wd0 = wedot[0], wd1 = wedot[1], wd2 = wedot[2], wd3 = wedot[3];
      float wdP = sel4(wd0, wd1, wd2, wd3, lh);

      float Z[4] = {0.f, 0.f, 0.f, 0.f};
      float denP = 0.f;
      float easumP = 0.f;

      for (int i = 0; i < cnt; i += 16) {
        // ---- Phase A load: one record per 4-lane group (chunk 0 prefetched)
        int slot = i + le;
        bool av = slot < cnt;
        int2 re = (i == 0) ? preRe : ebuf[eidx(node, i >> 4, le, n)];
        int srcE = av ? re.x : 0;
        float ev = av ? __int_as_float(re.y) : 0.f;
        // ---- broadcast srcs NOW; x gathers issue before the exp chain
        int srcK[4];
        float xvK[4];
#pragma unroll
        for (int k = 0; k < 4; k++) srcK[k] = __shfl(srcE, (k * 4 + es) * 4, 64);
#pragma unroll
        for (int k = 0; k < 4; k++) xvK[k] = x[(size_t)srcK[k] * 16 + c];
        // ---- weight chain (parallel with x gathers)
        float a = al0s[(size_t)srcE * 4 + lh] + aldP + ev * wdP;
        a = fmaxf(a, 0.2f * a);
        a = fminf(a, 30.f);
        float wE = av ? __expf(a) : 0.f;
        denP += wE;
        easumP += (lh == 0) ? ev : 0.f;
        // ---- accumulate: weights via shfl (same order as R20)
#pragma unroll
        for (int k = 0; k < 4; k++) {
          int e4 = (k * 4 + es) * 4;
          float w0v = __shfl(wE, e4 + 0, 64);
          float w1v = __shfl(wE, e4 + 1, 64);
          float w2v = __shfl(wE, e4 + 2, 64);
          float w3v = __shfl(wE, e4 + 3, 64);
          Z[0] = fmaf(w0v, xvK[k], Z[0]);
          Z[1] = fmaf(w1v, xvK[k], Z[1]);
          Z[2] = fmaf(w2v, xvK[k], Z[2]);
          Z[3] = fmaf(w3v, xvK[k], Z[3]);
        }
      }

      // prefetch next node's first record (overlaps reduce + epilogue)
      if (s < 3) preRe = ebuf[eidx(node + 1 < n ? node + 1 : n - 1, 0, le, n)];

      // reduce Z over the 4 es-groups (same order as R20)
#pragma unroll
      for (int h = 0; h < 4; h++) {
        Z[h] += __shfl_xor(Z[h], 16, 64);
        Z[h] += __shfl_xor(Z[h], 32, 64);
      }
      // reduce den over le-lanes (per lh); easum over all lanes
      denP += __shfl_xor(denP, 4, 64);
      denP += __shfl_xor(denP, 8, 64);
      denP += __shfl_xor(denP, 16, 64);
      denP += __shfl_xor(denP, 32, 64);
      float easum = wave_sum(easumP);

      // per-lane head = es: den total + self loop (single exp)
      float dsel = __shfl(denP, es, 64);
      float evs = easum / fmaxf((float)dg, 1.f);
      float as_e = sel4(as4s.x, as4s.y, as4s.z, as4s.w, es);
      float ald_e = sel4(ald4.x, ald4.y, ald4.z, ald4.w, es);
      float wd_e = sel4(wd0, wd1, wd2, wd3, es);
      float aS = as_e + ald_e + evs * wd_e;
      aS = fmaxf(aS, 0.2f * aS);
      aS = fminf(aS, 30.f);
      float wvs = __expf(aS);
      dsel += wvs;
      float zsel = sel4(Z[0], Z[1], Z[2], Z[3], es) + wvs * xself;
      float zn = zsel / (dsel + 1e-16f);

      float zc[16];
      int basel = lane & 48;
#pragma unroll
      for (int cc = 0; cc < 16; cc++) zc[cc] = __shfl(zn, basel + cc, 64);
      float o[4];
      float4 b4 = ((const float4*)b0)[lane];
#pragma unroll
      for (int jj = 0; jj < 4; jj++) o[jj] = ((const float*)&b4)[jj];
#pragma unroll
      for (int cc = 0; cc < 16; cc++) {
        float4 w0r = *(const float4*)&w0lds[cc * 256 + lane * 4];
#pragma unroll
        for (int jj = 0; jj < 4; jj++) o[jj] = fmaf(zc[cc], ((const float*)&w0r)[jj], o[jj]);
      }
      ushort4 o4;
      float ox = o[0] > 0.f ? o[0] : expm1f(o[0]);
      float oy = o[1] > 0.f ? o[1] : expm1f(o[1]);
      float oz = o[2] > 0.f ? o[2] : expm1f(o[2]);
      float ow = o[3] > 0.f ? o[3] : expm1f(o[3]);
      o4.x = f2bf(ox);
      o4.y = f2bf(oy);
      o4.z = f2bf(oz);
      o4.w = f2bf(ow);
      *(ushort4*)&hrow[r][lane * 4] = o4;
    } else {
      *(ushort4*)&hrow[r][lane * 4] = make_ushort4(0, 0, 0, 0);
    }
  }
  __syncthreads();

  // ---- block-level gemm1 over the 16-row LDS tile
  int m = lane & 15, q = lane >> 4;
  int row0 = tile * 16;
  short8 afrag[8];
#pragma unroll
  for (int ks = 0; ks < 8; ks++) afrag[ks] = *(short8*)&hrow[m][ks * 32 + q * 8];

  const short8* wf = (const short8*)Wf1;
  for (int nt = wv; nt < 17; nt += 4) {
    const short8* bl = wf + (size_t)nt * 8 * 64 + lane;
    short8 bf[8];
#pragma unroll
    for (int ks = 0; ks < 8; ks++) bf[ks] = bl[ks * 64];
    float4v acc = {0.f, 0.f, 0.f, 0.f};
#pragma unroll
    for (int ks = 0; ks < 8; ks++)
      acc = __builtin_amdgcn_mfma_f32_16x16x32_bf16(afrag[ks], bf[ks], acc, 0, 0, 0);
    if (nt < 16) {
      int col = nt * 16 + m;
#pragma unroll
      for (int reg = 0; reg < 4; reg++) {
        int rr = row0 + q * 4 + reg;
        if (rr < n) buf256[(size_t)rr * 256 + col] = f2bf(acc[reg]);
      }
    } else {
#pragma unroll
      for (int reg = 0; reg < 4; reg++) {
        int rr = row0 + q * 4 + reg;
        if (rr < n) {
          if (m < 4) al1s[(size_t)rr * 4 + m] = acc[reg];
          else if (m < 8) al1d[(size_t)rr * 4 + (m - 4)] = acc[reg];
        }
      }
    }
  }
}

// fused1: layer-1 aggregation (shfl weights, early row-gathers, cross-node
// prefetch) -> LDS row, then gemm2 -> buf64 + al2s/al2d.
__global__ __launch_bounds__(256) void fused1_kernel(
    const int* __restrict__ deg, const int2* __restrict__ ebuf,
    const float* __restrict__ al1s, const float* __restrict__ al1d,
    const float* __restrict__ wedot,
    const unsigned short* __restrict__ buf256, const float* __restrict__ b1,
    const unsigned short* __restrict__ Wf2, unsigned short* __restrict__ buf64,
    float* __restrict__ al2s, float* __restrict__ al2d, int n) {
  __shared__ unsigned short hrow[16][264];  // 528B row stride
  int tile = blockIdx.x;
  int wv = threadIdx.x >> 6;
  int lane = threadIdx.x & 63;
  int half = lane >> 5;
  int l = lane & 31;
  int h4 = l >> 3;
  int le = lane >> 2;
  int lh = lane & 3;
  int eA0 = half ? 1 : 0;  // Phase-B edge offsets
  int eB0 = half ? 3 : 2;

  int node0 = tile * 16 + wv * 4;
  int2 preRe = ebuf[eidx(node0 < n ? node0 : n - 1, 0, le, n)];

  for (int s = 0; s < 4; s++) {
    int r = wv * 4 + s;
    int node = tile * 16 + r;
    if (node < n) {
      int dg = deg[node];
      int cnt = dg < CAP ? dg : CAP;
      float aldh = al1d[(size_t)node * 4 + h4];
      float alsh = al1s[(size_t)node * 4 + h4];
      float wdh = wedot[4 + h4];
      float aldP = al1d[(size_t)node * 4 + lh];
      float wdP = wedot[4 + lh];
      short8 rowS = ((const short8*)(buf256 + (size_t)node * 256))[l];

      float acc[8];
#pragma unroll
      for (int j = 0; j < 8; j++) acc[j] = 0.f;
      float denP = 0.f;
      float easumP = 0.f;

      for (int i = 0; i < cnt; i += 16) {
        // ---- Phase A load (chunk 0 prefetched)
        int slot = i + le;
        bool av = slot < cnt;
        int2 re = (i == 0) ? preRe : ebuf[eidx(node, i >> 4, le, n)];
        int srcE = av ? re.x : 0;
        float ev = av ? __int_as_float(re.y) : 0.f;
        // ---- broadcast srcs NOW; 512B row gathers issue before exp chain
        int srcA[4], srcB[4];
#pragma unroll
        for (int k = 0; k < 4; k++) {
          srcA[k] = __shfl(srcE, (k * 4 + eA0) * 4, 64);
          srcB[k] = __shfl(srcE, (k * 4 + eB0) * 4, 64);
        }
        short8 rowA[4], rowB[4];
#pragma unroll
        for (int k = 0; k < 4; k++) {
          rowA[k] = ((const short8*)(buf256 + (size_t)srcA[k] * 256))[l];
          rowB[k] = ((const short8*)(buf256 + (size_t)srcB[k] * 256))[l];
        }
        // ---- weight chain (parallel with row gathers)
        float a = al1s[(size_t)srcE * 4 + lh] + aldP + ev * wdP;
        a = fmaxf(a, 0.2f * a);
        a = fminf(a, 30.f);
        float wE = av ? __expf(a) : 0.f;
        denP += wE;
        easumP += (lh == 0) ? ev : 0.f;
        // ---- accumulate (same order as R20: eA then eB per k)
#pragma unroll
        for (int k = 0; k < 4; k++) {
          float wA = __shfl(wE, (k * 4 + eA0) * 4 + h4, 64);
          float wB = __shfl(wE, (k * 4 + eB0) * 4 + h4, 64);
          const unsigned short* pa = (const unsigned short*)&rowA[k];
          const unsigned short* pb = (const unsigned short*)&rowB[k];
#pragma unroll
          for (int j = 0; j < 8; j++) acc[j] = fmaf(wA, bf2f(pa[j]), acc[j]);
#pragma unroll
          for (int j = 0; j < 8; j++) acc[j] = fmaf(wB, bf2f(pb[j]), acc[j]);
        }
      }

      // prefetch next node's first record (overlaps reduce + epilogue)
      if (s < 3) preRe = ebuf[eidx(node + 1 < n ? node + 1 : n - 1, 0, le, n)];

      // merge halves (same as R20)
#pragma unroll
      for (int j = 0; j < 8; j++) acc[j] += __shfl_xor(acc[j], 32, 64);
      // den per head; easum over all
      denP += __shfl_xor(denP, 4, 64);
      denP += __shfl_xor(denP, 8, 64);
      denP += __shfl_xor(denP, 16, 64);
      denP += __shfl_xor(denP, 32, 64);
      float easum = wave_sum(easumP);
      float den = __shfl(denP, h4, 64);

      {  // self loop (single exp per lane, head h4)
        float evs = easum / fmaxf((float)dg, 1.f);
        float a = alsh + aldh + evs * wdh;
        a = fmaxf(a, 0.2f * a);
        a = fminf(a, 30.f);
        float wvv = __expf(a);
        const unsigned short* ps = (const unsigned short*)&rowS;
        den += wvv;
#pragma unroll
        for (int j = 0; j < 8; j++) acc[j] = fmaf(wvv, bf2f(ps[j]), acc[j]);
      }

      if (half == 0) {
        float inv = 1.f / (den + 1e-16f);
        float4 bb0 = ((const float4*)b1)[l * 2];
        float4 bb1 = ((const float4*)b1)[l * 2 + 1];
        unsigned short o8[8];
#pragma unroll
        for (int j = 0; j < 8; j++) {
          float bjv = (j < 4) ? ((const float*)&bb0)[j] : ((const float*)&bb1)[j - 4];
          float o = acc[j] * inv + bjv;
          o = o > 0.f ? o : expm1f(o);
          o8[j] = f2bf(o);
        }
        *(short8*)&hrow[r][l * 8] = *(short8*)o8;
      }
    } else if ((lane >> 5) == 0) {
      unsigned short z8[8] = {0, 0, 0, 0, 0, 0, 0, 0};
      *(short8*)&hrow[r][(lane & 31) * 8] = *(short8*)z8;
    }
  }
  __syncthreads();

  // ---- block-level gemm2 over the 16-row LDS tile
  int m = lane & 15, q = lane >> 4;
  int row0 = tile * 16;
  short8 afrag[8];
#pragma unroll
  for (int ks = 0; ks < 8; ks++) afrag[ks] = *(short8*)&hrow[m][ks * 32 + q * 8];

  const short8* wf = (const short8*)Wf2;
  for (int nt = wv; nt < 5; nt += 4) {
    const short8* bl = wf + (size_t)nt * 8 * 64 + lane;
    short8 bf[8];
#pragma unroll
    for (int ks = 0; ks < 8; ks++) bf[ks] = bl[ks * 64];
    float4v acc = {0.f, 0.f, 0.f, 0.f};
#pragma unroll
    for (int ks = 0; ks < 8; ks++)
      acc = __builtin_amdgcn_mfma_f32_16x16x32_bf16(afrag[ks], bf[ks], acc, 0, 0, 0);
    if (nt < 4) {
      int col = nt * 16 + m;
#pragma unroll
      for (int reg = 0; reg < 4; reg++) {
        int rr = row0 + q * 4 + reg;
        if (rr < n) buf64[(size_t)rr * 64 + col] = f2bf(acc[reg]);
      }
    } else {
#pragma unroll
      for (int reg = 0; reg < 4; reg++) {
        int rr = row0 + q * 4 + reg;
        if (rr < n) {
          if (m < 1) al2s[rr] = acc[reg];
          else if (m < 2) al2d[rr] = acc[reg];
        }
      }
    }
  }
}

// H=1 aggregation (shfl weights, early gathers) + bias + LayerNorm.
__global__ __launch_bounds__(256) void agg_ln_kernel(
    const int* __restrict__ deg, const int2* __restrict__ ebuf,
    const float* __restrict__ al2s, const float* __restrict__ al2d,
    const float* __restrict__ wedot,
    const unsigned short* __restrict__ B, const float* __restrict__ bias,
    const float* __restrict__ ln_g, const float* __restrict__ ln_b,
    float* __restrict__ out, int n) {
  int wv = threadIdx.x >> 6;
  int node = blockIdx.x * 4 + wv;
  if (node >= n) return;
  int lane = threadIdx.x & 63;
  int q = lane >> 4;
  int l = lane & 15;
  int le = lane & 15;  // Phase-A edge (4x redundant groups; exact dup-sum)
  int dg = deg[node];
  int cnt = dg < CAP ? dg : CAP;
  float ald = al2d[node];
  float als = al2s[node];
  float wd = wedot[0];
  ushort4 bvS = ((const ushort4*)(B + (size_t)node * 64))[l];

  float4 acc = make_float4(0.f, 0.f, 0.f, 0.f);
  float denP = 0.f;
  float easumP = 0.f;

  for (int i = 0; i < cnt; i += 16) {
    int slot = i + le;
    bool av = slot < cnt;
    int2 re = ebuf[eidx(node, i >> 4, le, n)];
    int srcE = av ? re.x : 0;
    float ev = av ? __int_as_float(re.y) : 0.f;
    int srcK[4];
#pragma unroll
    for (int k = 0; k < 4; k++) srcK[k] = __shfl(srcE, k * 4 + q, 64);
    ushort4 bvK[4];
#pragma unroll
    for (int k = 0; k < 4; k++) bvK[k] = ((const ushort4*)(B + (size_t)srcK[k] * 64))[l];
    float a = al2s[srcE] + ald + ev * wd;
    a = fmaxf(a, 0.2f * a);
    a = fminf(a, 30.f);
    float wE = av ? __expf(a) : 0.f;
    denP += wE;    // 4 copies per edge -> exact /4 later
    easumP += ev;  // ditto
#pragma unroll
    for (int k = 0; k < 4; k++) {
      float w = __shfl(wE, k * 4 + q, 64);
      acc.x = fmaf(w, bf2f(bvK[k].x), acc.x);
      acc.y = fmaf(w, bf2f(bvK[k].y), acc.y);
      acc.z = fmaf(w, bf2f(bvK[k].z), acc.z);
      acc.w = fmaf(w, bf2f(bvK[k].w), acc.w);
    }
  }

  acc.x += __shfl_xor(acc.x, 32, 64);
  acc.y += __shfl_xor(acc.y, 32, 64);
  acc.z += __shfl_xor(acc.z, 32, 64);
  acc.w += __shfl_xor(acc.w, 32, 64);
  acc.x += __shfl_xor(acc.x, 16, 64);
  acc.y += __shfl_xor(acc.y, 16, 64);
  acc.z += __shfl_xor(acc.z, 16, 64);
  acc.w += __shfl_xor(acc.w, 16, 64);
  float den = wave_sum(denP) * 0.25f;
  float easum = wave_sum(easumP) * 0.25f;

  {  // self loop (single exp)
    float evs = easum / fmaxf((float)dg, 1.f);
    float a = als + ald + evs * wd;
    a = fmaxf(a, 0.2f * a);
    a = fminf(a, 30.f);
    float wv2 = __expf(a);
    den += wv2;
    acc.x = fmaf(wv2, bf2f(bvS.x), acc.x);
    acc.y = fmaf(wv2, bf2f(bvS.y), acc.y);
    acc.z = fmaf(wv2, bf2f(bvS.z), acc.z);
    acc.w = fmaf(wv2, bf2f(bvS.w), acc.w);
  }

  float inv = 1.f / (den + 1e-16f);
  float4 b4 = ((const float4*)bias)[l];
  float4 o;
  o.x = acc.x * inv + b4.x;
  o.y = acc.y * inv + b4.y;
  o.z = acc.z * inv + b4.z;
  o.w = acc.w * inv + b4.w;
  float s = (o.x + o.y) + (o.z + o.w);
#pragma unroll
  for (int off = 1; off < 16; off <<= 1) s += __shfl_xor(s, off, 64);
  float mu = s * (1.f / 64.f);
  float dx = o.x - mu, dy = o.y - mu, dz = o.z - mu, dw = o.w - mu;
  float v = (dx * dx + dy * dy) + (dz * dz + dw * dw);
#pragma unroll
  for (int off = 1; off < 16; off <<= 1) v += __shfl_xor(v, off, 64);
  float rs = rsqrtf(v * (1.f / 64.f) + 1e-5f);
  if (q == 0) {
    float4 g4 = ((const float4*)ln_g)[l];
    float4 lb4 = ((const float4*)ln_b)[l];
    float4 rr;
    rr.x = dx * rs * g4.x + lb4.x;
    rr.y = dy * rs * g4.y + lb4.y;
    rr.z = dz * rs * g4.z + lb4.z;
    rr.w = dw * rs * g4.w + lb4.w;
    ((float4*)(out + (size_t)node * 64))[l] = rr;
  }
}

extern "C" void kernel_launch(void* const* d_in, const int* in_sizes, int n_in,
                              void* d_out, int out_size, void* d_ws, size_t ws_size,
                              hipStream_t stream) {
  const float* x = (const float*)d_in[0];
  const int* ei = (const int*)d_in[1];
  const float* eattr = (const float*)d_in[2];
  const float* W0 = (const float*)d_in[3];
  const float* as0 = (const float*)d_in[4];
  const float* ad0 = (const float*)d_in[5];
  const float* We0 = (const float*)d_in[6];
  const float* ae0 = (const float*)d_in[7];
  const float* b0 = (const float*)d_in[8];
  const float* W1 = (const float*)d_in[9];
  const float* as1 = (const float*)d_in[10];
  const float* ad1 = (const float*)d_in[11];
  const float* We1 = (const float*)d_in[12];
  const float* ae1 = (const float*)d_in[13];
  const float* b1 = (const float*)d_in[14];
  const float* W2 = (const float*)d_in[15];
  const float* as2 = (const float*)d_in[16];
  const float* ad2 = (const float*)d_in[17];
  const float* We2 = (const float*)d_in[18];
  const float* ae2 = (const float*)d_in[19];
  const float* b2 = (const float*)d_in[20];
  const float* lng = (const float*)d_in[21];
  const float* lnb = (const float*)d_in[22];
  float* outp = (float*)d_out;

  const int N = in_sizes[0] / 16;
  const int E = in_sizes[1] / 2;
  const int* srcv = ei;
  const int* dstv = ei + E;

  char* w = (char*)d_ws;
  size_t off = 0;
  auto alloc = [&](size_t bytes) -> void* {
    void* p = w + off;
    off += (bytes + 255) & ~(size_t)255;
    return p;
  };
  int* deg = (int*)alloc((size_t)N * 4);
  size_t zero_bytes = off;  // deg must start at 0
  int2* ebuf = (int2*)alloc(((size_t)N * CAP + 16) * 8);  // +16: overread pad
  float* wedot = (float*)alloc(16 * 4);
  float* al0s = (float*)alloc((size_t)N * 4 * 4);
  float* al0d = (float*)alloc((size_t)N * 4 * 4);
  float* al1s = (float*)alloc((size_t)N * 4 * 4);
  float* al1d = (float*)alloc((size_t)N * 4 * 4);
  float* al2s = (float*)alloc((size_t)N * 4);
  float* al2d = (float*)alloc((size_t)N * 4);
  unsigned short* Wf1 = (unsigned short*)alloc((size_t)17 * 4096 * 2);
  unsigned short* Wf2 = (unsigned short*)alloc((size_t)5 * 4096 * 2);
  unsigned short* buf256 = (unsigned short*)alloc((size_t)N * 256 * 2);
  unsigned short* buf64 = (unsigned short*)alloc((size_t)N * 64 * 2);
  (void)ws_size;

  hipMemsetAsync(d_ws, 0, zero_bytes, stream);

  int gE = (E + 255) / 256;
  int gD = (N + 255) / 256;

  k1_kernel<<<353 + gD + gE, 256, 0, stream>>>(
      x, srcv, dstv, eattr, W0, as0, ad0, We0, ae0, W1, as1, ad1, We1, ae1,
      W2, as2, ad2, We2, ae2, Wf1, Wf2, wedot, al0s, al0d, deg, ebuf, N, E, gD);

  int gT = (N + 15) / 16;
  int gNode4 = (N + 3) / 4;

  // ---- layer 0 + gemm1 fused
  fused0_kernel<<<gT, 256, 0, stream>>>(deg, ebuf, al0s, al0d, wedot, x, W0, b0,
                                        Wf1, buf256, al1s, al1d, N);

  // ---- layer 1 + gemm2 fused
  fused1_kernel<<<gT, 256, 0, stream>>>(deg, ebuf, al1s, al1d, wedot, buf256, b1,
                                        Wf2, buf64, al2s, al2d, N);

  // ---- layer 2 (+ LayerNorm -> d_out)
  agg_ln_kernel<<<gNode4, 256, 0, stream>>>(deg, ebuf, al2s, al2d, wedot + 8,
                                            buf64, b2, lng, lnb, outp, N);
}